// Round 2
// baseline (174.059 us; speedup 1.0000x reference)
//
#include <hip/hip_runtime.h>
#include <math.h>

namespace {
constexpr int kB     = 64;
constexpr int kH     = 32;
constexpr int kKVH   = 8;
constexpr int kG     = 4;     // H / KVH
constexpr int kD     = 128;
constexpr int kBS    = 128;
constexpr int kNBPS  = 16;
constexpr int kS     = 2048;
constexpr int kChunk = 256;   // positions per split = 2 cache blocks
constexpr int kNSplit = kS / kChunk;  // 8
constexpr float kScale = 0.08838834764831845f; // 1/sqrt(128)
}

// ---------------- Phase 1: per-chunk partial attention ----------------
__global__ __launch_bounds__(256)
void pa_partial(const float* __restrict__ q,
                const float* __restrict__ knew,
                const float* __restrict__ vnew,
                const float* __restrict__ kcache,
                const float* __restrict__ vcache,
                const int* __restrict__ block_tables,
                const int* __restrict__ ctx_lens,
                float* __restrict__ m_part,   // [B][KVH][NSPLIT][G]
                float* __restrict__ l_part,   // [B][KVH][NSPLIT][G]
                float* __restrict__ o_part)   // [B][KVH][NSPLIT][G][D]
{
  const int job   = blockIdx.x;
  const int split = job & (kNSplit - 1);
  const int kvh   = (job >> 3) & (kKVH - 1);
  const int b     = job >> 6;

  const int ctx   = ctx_lens[b];
  const int start = split * kChunk;
  if (start >= ctx) return;
  const int end   = min(ctx, start + kChunk);
  const int last  = ctx - 1;

  const int tid  = threadIdx.x;
  const int wave = tid >> 6;     // 4 waves
  const int lane = tid & 63;
  const int grp  = lane >> 5;    // 0: even pos of pair, 1: odd
  const int l32  = lane & 31;

  // the chunk spans exactly cache blocks 2*split, 2*split+1 (wave-uniform scalars)
  const int bt0 = block_tables[b * kNBPS + 2 * split];
  const int bt1 = block_tables[b * kNBPS + 2 * split + 1];

  __shared__ float red_m[4][kG];
  __shared__ float red_l[4][kG];
  __shared__ float red_acc[4][kG][kD];

  // q fragment: head g, dims [l32*4, l32*4+4)
  float4 qf[kG];
#pragma unroll
  for (int g = 0; g < kG; ++g)
    qf[g] = *reinterpret_cast<const float4*>(q + (b * kH + kvh * kG + g) * kD + l32 * 4);

  const float* knew_row = knew + (b * kKVH + kvh) * kD;
  const float* vnew_row = vnew + (b * kKVH + kvh) * kD;

  float  m[kG], l[kG];
  float2 acc[kG];   // lane owns d = lane*2, lane*2+1
#pragma unroll
  for (int g = 0; g < kG; ++g) { m[g] = -INFINITY; l[g] = 0.f; acc[g] = make_float2(0.f, 0.f); }

  const int npairs = (end - start + 1) >> 1;

  auto k_ptr = [&](int i) -> const float4* {
    const int pe  = start + i * 2;
    const bool ov = (pe + 1) < end;
    const int myp = (grp && ov) ? pe + 1 : pe;
    const float* kr;
    if (myp == last) kr = knew_row;
    else {
      const int blk = ((myp - start) >> 7) ? bt1 : bt0;
      kr = kcache + ((size_t)(blk * kBS + (myp & 127)) * kKVH + kvh) * kD;
    }
    return reinterpret_cast<const float4*>(kr + l32 * 4);
  };
  auto v_ptr = [&](int p) -> const float2* {
    const float* vr;
    if (p == last) vr = vnew_row;
    else {
      const int blk = ((p - start) >> 7) ? bt1 : bt0;
      vr = vcache + ((size_t)(blk * kBS + (p & 127)) * kKVH + kvh) * kD;
    }
    return reinterpret_cast<const float2*>(vr + lane * 2);
  };

  int i = wave;
  float4 kf = {};
  float2 ve = {}, vo = {};
  if (i < npairs) {
    const int pe  = start + i * 2;
    const bool ov = (pe + 1) < end;
    kf = *k_ptr(i);
    ve = *v_ptr(pe);
    vo = *v_ptr(ov ? pe + 1 : pe);
  }

  while (i < npairs) {
    const int pe  = start + i * 2;
    const bool ov = (pe + 1) < end;
    const bool myvalid = (!grp) || ov;
    const int inext = i + 4;

    // prefetch next pair (wave-uniform branch)
    float4 nkf = {};
    float2 nve = {}, nvo = {};
    if (inext < npairs) {
      const int npe  = start + inext * 2;
      const bool nov = (npe + 1) < end;
      nkf = *k_ptr(inext);
      nve = *v_ptr(npe);
      nvo = *v_ptr(nov ? npe + 1 : npe);
    }

    // ---- 4-head dot products, reduced over the 32-lane group ----
    float s[kG];
#pragma unroll
    for (int g = 0; g < kG; ++g) {
      s[g] = qf[g].x * kf.x;
      s[g] = fmaf(qf[g].y, kf.y, s[g]);
      s[g] = fmaf(qf[g].z, kf.z, s[g]);
      s[g] = fmaf(qf[g].w, kf.w, s[g]);
    }
#pragma unroll
    for (int off = 1; off < 32; off <<= 1) {
#pragma unroll
      for (int g = 0; g < kG; ++g) s[g] += __shfl_xor(s[g], off);
    }
#pragma unroll
    for (int g = 0; g < kG; ++g)
      s[g] = myvalid ? s[g] * kScale : -INFINITY;

    // exchange across the 32-boundary
    float se[kG], so[kG];
#pragma unroll
    for (int g = 0; g < kG; ++g) {
      const float s2 = __shfl_xor(s[g], 32);
      se[g] = grp ? s2   : s[g];
      so[g] = grp ? s[g] : s2;
    }

    // ---- online softmax + V accumulation ----
#pragma unroll
    for (int g = 0; g < kG; ++g) {
      const float pm = fmaxf(se[g], so[g]);
      if (pm > m[g]) {                        // wave-uniform
        const float cf = __expf(m[g] - pm);
        m[g] = pm;
        l[g] *= cf;
        acc[g].x *= cf;
        acc[g].y *= cf;
      }
      const float ee = __expf(se[g] - m[g]);
      const float eo = __expf(so[g] - m[g]);  // 0 if odd invalid
      l[g] += ee + eo;
      acc[g].x = fmaf(ee, ve.x, fmaf(eo, vo.x, acc[g].x));
      acc[g].y = fmaf(ee, ve.y, fmaf(eo, vo.y, acc[g].y));
    }

    kf = nkf; ve = nve; vo = nvo;
    i = inext;
  }

  // ---- combine 4 wave-local states ----
  if (lane == 0) {
#pragma unroll
    for (int g = 0; g < kG; ++g) { red_m[wave][g] = m[g]; red_l[wave][g] = l[g]; }
  }
#pragma unroll
  for (int g = 0; g < kG; ++g) {
    red_acc[wave][g][lane * 2]     = acc[g].x;
    red_acc[wave][g][lane * 2 + 1] = acc[g].y;
  }
  __syncthreads();

  const int g  = tid >> 6;        // 256 threads -> 4 heads x 64 dim-pairs
  const int dd = (tid & 63) * 2;
  float M = -INFINITY;
#pragma unroll
  for (int w = 0; w < 4; ++w) M = fmaxf(M, red_m[w][g]);
  float L = 0.f, o0 = 0.f, o1 = 0.f;
#pragma unroll
  for (int w = 0; w < 4; ++w) {
    const float f = __expf(red_m[w][g] - M);   // 0 for empty waves
    L  = fmaf(f, red_l[w][g], L);
    o0 = fmaf(f, red_acc[w][g][dd], o0);
    o1 = fmaf(f, red_acc[w][g][dd + 1], o1);
  }
  const size_t idx = ((size_t)((b * kKVH + kvh) * kNSplit + split)) * kG + g;
  if ((tid & 63) == 0) { m_part[idx] = M; l_part[idx] = L; }
  o_part[idx * kD + dd]     = o0;
  o_part[idx * kD + dd + 1] = o1;
}

// ---------------- Phase 2: combine splits ----------------
__global__ __launch_bounds__(512)
void pa_reduce(const float* __restrict__ m_part,
               const float* __restrict__ l_part,
               const float* __restrict__ o_part,
               const int* __restrict__ ctx_lens,
               float* __restrict__ out)
{
  const int job = blockIdx.x;     // b*KVH + kvh
  const int b   = job >> 3;
  const int kvh = job & 7;
  const int tid = threadIdx.x;
  const int g   = tid >> 7;       // 512 threads: 4 heads x 128 dims
  const int d   = tid & 127;
  const int ctx  = ctx_lens[b];
  const int nact = (ctx + kChunk - 1) / kChunk;

  const size_t base = (size_t)job * kNSplit * kG + g;
  float M = -INFINITY;
  for (int s = 0; s < nact; ++s) M = fmaxf(M, m_part[base + (size_t)s * kG]);
  float L = 0.f, o = 0.f;
  for (int s = 0; s < nact; ++s) {
    const size_t idx = base + (size_t)s * kG;
    const float f = __expf(m_part[idx] - M);
    L = fmaf(f, l_part[idx], L);
    o = fmaf(f, o_part[idx * kD + d], o);
  }
  out[((b * kH) + kvh * kG + g) * kD + d] = o / L;
}

// ---------------- Fallback: round-1 single kernel (if ws too small) ----------------
__global__ __launch_bounds__(512, 4)
void pa_decode_kernel(const float* __restrict__ q,
                      const float* __restrict__ knew,
                      const float* __restrict__ vnew,
                      const float* __restrict__ kcache,
                      const float* __restrict__ vcache,
                      const int* __restrict__ block_tables,
                      const int* __restrict__ ctx_lens,
                      float* __restrict__ out)
{
  const int job  = blockIdx.x;
  const int b    = job >> 3;
  const int kvh  = job & 7;
  const int tid  = threadIdx.x;
  const int wave = tid >> 6;
  const int lane = tid & 63;
  const int grp  = lane >> 5;
  const int l32  = lane & 31;

  __shared__ int   bt[kNBPS];
  __shared__ float red_m[8][kG];
  __shared__ float red_l[8][kG];
  __shared__ float red_acc[8][kG][kD];

  if (tid < kNBPS) bt[tid] = block_tables[b * kNBPS + tid];
  const int ctx = ctx_lens[b];
  __syncthreads();

  float4 qf[kG];
#pragma unroll
  for (int g = 0; g < kG; ++g)
    qf[g] = *reinterpret_cast<const float4*>(q + (b * kH + kvh * kG + g) * kD + l32 * 4);

  float  m[kG], l[kG];
  float2 acc[kG];
#pragma unroll
  for (int g = 0; g < kG; ++g) { m[g] = -INFINITY; l[g] = 0.f; acc[g] = make_float2(0.f, 0.f); }

  const float* knew_row = knew + (b * kKVH + kvh) * kD;
  const float* vnew_row = vnew + (b * kKVH + kvh) * kD;
  const int last   = ctx - 1;
  const int npairs = (ctx + 1) >> 1;

  for (int pair = wave; pair < npairs; pair += 8) {
    const int  pe      = pair * 2;
    const bool ovalid  = (pe + 1) < ctx;
    const int  myp     = (grp && ovalid) ? (pe + 1) : pe;
    const bool myvalid = (!grp) || ovalid;

    const float* krow = (myp == last) ? knew_row
        : kcache + ((size_t)(bt[myp >> 7] * kBS + (myp & 127)) * kKVH + kvh) * kD;
    const float4 kf = *reinterpret_cast<const float4*>(krow + l32 * 4);

    const int poc = ovalid ? (pe + 1) : pe;
    const float* vrow_e = (pe == last) ? vnew_row
        : vcache + ((size_t)(bt[pe >> 7] * kBS + (pe & 127)) * kKVH + kvh) * kD;
    const float* vrow_o = (poc == last) ? vnew_row
        : vcache + ((size_t)(bt[poc >> 7] * kBS + (poc & 127)) * kKVH + kvh) * kD;
    const float2 ve = *reinterpret_cast<const float2*>(vrow_e + lane * 2);
    const float2 vo = *reinterpret_cast<const float2*>(vrow_o + lane * 2);

    float s[kG];
#pragma unroll
    for (int g = 0; g < kG; ++g) {
      s[g] = qf[g].x * kf.x;
      s[g] = fmaf(qf[g].y, kf.y, s[g]);
      s[g] = fmaf(qf[g].z, kf.z, s[g]);
      s[g] = fmaf(qf[g].w, kf.w, s[g]);
    }
#pragma unroll
    for (int off = 1; off < 32; off <<= 1) {
#pragma unroll
      for (int g = 0; g < kG; ++g) s[g] += __shfl_xor(s[g], off);
    }
#pragma unroll
    for (int g = 0; g < kG; ++g)
      s[g] = myvalid ? s[g] * kScale : -INFINITY;

    float se[kG], so[kG];
#pragma unroll
    for (int g = 0; g < kG; ++g) {
      const float s2 = __shfl_xor(s[g], 32);
      se[g] = grp ? s2   : s[g];
      so[g] = grp ? s[g] : s2;
    }

#pragma unroll
    for (int g = 0; g < kG; ++g) {
      const float pm = fmaxf(se[g], so[g]);
      if (pm > m[g]) {
        const float cf = __expf(m[g] - pm);
        m[g] = pm;
        l[g] *= cf;
        acc[g].x *= cf;
        acc[g].y *= cf;
      }
      const float ee = __expf(se[g] - m[g]);
      const float eo = __expf(so[g] - m[g]);
      l[g] += ee + eo;
      acc[g].x = fmaf(ee, ve.x, fmaf(eo, vo.x, acc[g].x));
      acc[g].y = fmaf(ee, ve.y, fmaf(eo, vo.y, acc[g].y));
    }
  }

  if (lane == 0) {
#pragma unroll
    for (int g = 0; g < kG; ++g) { red_m[wave][g] = m[g]; red_l[wave][g] = l[g]; }
  }
#pragma unroll
  for (int g = 0; g < kG; ++g) {
    red_acc[wave][g][lane * 2]     = acc[g].x;
    red_acc[wave][g][lane * 2 + 1] = acc[g].y;
  }
  __syncthreads();

  const int g = tid >> 7;
  const int d = tid & 127;
  float M = -INFINITY;
#pragma unroll
  for (int w = 0; w < 8; ++w) M = fmaxf(M, red_m[w][g]);
  float L = 0.f, o = 0.f;
#pragma unroll
  for (int w = 0; w < 8; ++w) {
    const float f = __expf(red_m[w][g] - M);
    L = fmaf(f, red_l[w][g], L);
    o = fmaf(f, red_acc[w][g][d], o);
  }
  out[(b * kH + kvh * kG + g) * kD + d] = o / L;
}

extern "C" void kernel_launch(void* const* d_in, const int* in_sizes, int n_in,
                              void* d_out, int out_size, void* d_ws, size_t ws_size,
                              hipStream_t stream) {
  const float* q  = (const float*)d_in[0];
  const float* k  = (const float*)d_in[1];
  const float* v  = (const float*)d_in[2];
  const float* kc = (const float*)d_in[3];
  const float* vc = (const float*)d_in[4];
  // d_in[5] = slot_mapping (derivable; unused)
  const int* block_tables = (const int*)d_in[6];
  const int* ctx_lens     = (const int*)d_in[7];
  float* out = (float*)d_out;

  const size_t npart = (size_t)kB * kKVH * kNSplit * kG;            // 16384
  const size_t need  = (npart * 2 + npart * kD) * sizeof(float);    // ~8.5 MB
  if (ws_size >= need) {
    float* m_part = (float*)d_ws;
    float* l_part = m_part + npart;
    float* o_part = l_part + npart;
    pa_partial<<<kB * kKVH * kNSplit, 256, 0, stream>>>(
        q, k, v, kc, vc, block_tables, ctx_lens, m_part, l_part, o_part);
    pa_reduce<<<kB * kKVH, 512, 0, stream>>>(m_part, l_part, o_part, ctx_lens, out);
  } else {
    pa_decode_kernel<<<kB * kKVH, 512, 0, stream>>>(q, k, v, kc, vc,
                                                    block_tables, ctx_lens, out);
  }
}